// Round 2
// baseline (974.526 us; speedup 1.0000x reference)
//
#include <hip/hip_runtime.h>
#include <math.h>

// Problem constants
#define BATCH 2
#define HW 128          // H == W
#define CDIM 256
#define LTOK 16384      // HW*HW
#define MTOK 32768      // BATCH*LTOK
#define HEADS 8
#define DH 32
#define WINSZ 8
#define NWIN 64         // tokens per window
#define HID 1024

typedef unsigned int  u32;
typedef unsigned short u16;   // bf16 storage

__device__ __forceinline__ float gelu_f(float v) {
    return 0.5f * v * (1.f + erff(v * 0.70710678118654752f));
}

__device__ __forceinline__ u16 f2bf(float f) {
    u32 u = __float_as_uint(f);
    u32 r = (u + 0x7fffu + ((u >> 16) & 1u)) >> 16;   // round-to-nearest-even
    return (u16)r;
}

// ---- generic 4-wide load/store: fp32 or bf16 ------------------------------
__device__ __forceinline__ float4 ld4(const float* p) { return *(const float4*)p; }
__device__ __forceinline__ float4 ld4(const u16* p) {
    uint2 v = *(const uint2*)p;
    float4 r;
    r.x = __uint_as_float((v.x & 0xffffu) << 16);
    r.y = __uint_as_float(v.x & 0xffff0000u);
    r.z = __uint_as_float((v.y & 0xffffu) << 16);
    r.w = __uint_as_float(v.y & 0xffff0000u);
    return r;
}
__device__ __forceinline__ void st4(float* p, float4 v) { *(float4*)p = v; }
__device__ __forceinline__ void st4(u16* p, float4 v) {
    uint2 o;
    o.x = (u32)f2bf(v.x) | ((u32)f2bf(v.y) << 16);
    o.y = (u32)f2bf(v.z) | ((u32)f2bf(v.w) << 16);
    *(uint2*)p = o;
}

// ---------------------------------------------------------------------------
// LayerNorm over C=256: one wave (64 lanes) per row, 4 rows per 256-thr block
// ---------------------------------------------------------------------------
template<typename TI, typename TO>
__global__ __launch_bounds__(256) void ln_kernel(
    const TI* __restrict__ x, const float* __restrict__ g,
    const float* __restrict__ b, TO* __restrict__ y)
{
    int wave = threadIdx.x >> 6;
    int lane = threadIdx.x & 63;
    int row = blockIdx.x * 4 + wave;
    const TI* xr = x + (size_t)row * CDIM;
    float4 v = ld4(&xr[lane * 4]);
    float s  = v.x + v.y + v.z + v.w;
    float s2 = v.x*v.x + v.y*v.y + v.z*v.z + v.w*v.w;
    #pragma unroll
    for (int off = 32; off > 0; off >>= 1) {
        s  += __shfl_xor(s,  off);
        s2 += __shfl_xor(s2, off);
    }
    float mu   = s * (1.f / CDIM);
    float var  = s2 * (1.f / CDIM) - mu * mu;
    float rstd = rsqrtf(var + 1e-5f);
    float4 gv = *(const float4*)&g[lane * 4];
    float4 bv = *(const float4*)&b[lane * 4];
    float4 o;
    o.x = (v.x - mu) * rstd * gv.x + bv.x;
    o.y = (v.y - mu) * rstd * gv.y + bv.y;
    o.z = (v.z - mu) * rstd * gv.z + bv.z;
    o.w = (v.w - mu) * rstd * gv.w + bv.w;
    st4(&y[(size_t)row * CDIM + lane * 4], o);
}

// ---------------------------------------------------------------------------
// Tiled fp32-compute GEMM: C[M,N] = A[M,K] @ B[K,N] + bias (+res / +gelu)
// BM=BN=64, BK=16, 256 threads, 4x4 accumulators per thread.
// A/res/C may each be fp32 or bf16 (template). B (weights) fp32.
// EPI: 0 = bias, 1 = bias + residual, 2 = bias + GELU
// ---------------------------------------------------------------------------
template<int EPI, typename TA, typename TR, typename TO>
__global__ __launch_bounds__(256) void gemm_kernel(
    const TA* __restrict__ A, const float* __restrict__ Bw,
    const float* __restrict__ bias, const TR* __restrict__ res,
    TO* __restrict__ Cc, int N, int K)
{
    constexpr int BM = 64, BN = 64, BK = 16;
    __shared__ float As[BK][BM + 4];
    __shared__ float Bs[BK][BN + 4];
    int tid = threadIdx.x;
    int bm = blockIdx.y * BM;
    int bn = blockIdx.x * BN;
    int tx = tid & 15;         // output col group
    int ty = tid >> 4;         // output row group
    int a_row  = tid >> 2;     // 0..63
    int a_kc   = (tid & 3) * 4;
    int b_krow = tid >> 4;     // 0..15
    int b_col  = (tid & 15) * 4;

    float acc[4][4] = {};

    for (int kt = 0; kt < K; kt += BK) {
        float4 av = ld4(&A[(size_t)(bm + a_row) * K + kt + a_kc]);
        As[a_kc + 0][a_row] = av.x;
        As[a_kc + 1][a_row] = av.y;
        As[a_kc + 2][a_row] = av.z;
        As[a_kc + 3][a_row] = av.w;
        float4 bv = *(const float4*)&Bw[(size_t)(kt + b_krow) * N + bn + b_col];
        *(float4*)&Bs[b_krow][b_col] = bv;
        __syncthreads();
        #pragma unroll
        for (int k = 0; k < BK; ++k) {
            float a0 = As[k][ty * 4 + 0];
            float a1 = As[k][ty * 4 + 1];
            float a2 = As[k][ty * 4 + 2];
            float a3 = As[k][ty * 4 + 3];
            float b0 = Bs[k][tx * 4 + 0];
            float b1 = Bs[k][tx * 4 + 1];
            float b2 = Bs[k][tx * 4 + 2];
            float b3 = Bs[k][tx * 4 + 3];
            acc[0][0] += a0 * b0; acc[0][1] += a0 * b1; acc[0][2] += a0 * b2; acc[0][3] += a0 * b3;
            acc[1][0] += a1 * b0; acc[1][1] += a1 * b1; acc[1][2] += a1 * b2; acc[1][3] += a1 * b3;
            acc[2][0] += a2 * b0; acc[2][1] += a2 * b1; acc[2][2] += a2 * b2; acc[2][3] += a2 * b3;
            acc[3][0] += a3 * b0; acc[3][1] += a3 * b1; acc[3][2] += a3 * b2; acc[3][3] += a3 * b3;
        }
        __syncthreads();
    }

    float4 bias4 = *(const float4*)&bias[bn + tx * 4];
    #pragma unroll
    for (int i = 0; i < 4; ++i) {
        int row = bm + ty * 4 + i;
        float v0 = acc[i][0] + bias4.x;
        float v1 = acc[i][1] + bias4.y;
        float v2 = acc[i][2] + bias4.z;
        float v3 = acc[i][3] + bias4.w;
        if (EPI == 1) {
            float4 rv = ld4(&res[(size_t)row * N + bn + tx * 4]);
            v0 += rv.x; v1 += rv.y; v2 += rv.z; v3 += rv.w;
        }
        if (EPI == 2) {
            v0 = gelu_f(v0); v1 = gelu_f(v1); v2 = gelu_f(v2); v3 = gelu_f(v3);
        }
        st4(&Cc[(size_t)row * N + bn + tx * 4], make_float4(v0, v1, v2, v3));
    }
}

// ---------------------------------------------------------------------------
// Windowed attention, one 64-thread block per (window, head).
// Gathers q/k/v from qkv[token,768] with shifted-window indexing; scatters the
// attention output back at the same token (shift+partition == its inverse's
// gather), so everything else runs in plain token order.
// ---------------------------------------------------------------------------
__global__ __launch_bounds__(64) void attn_kernel(
    const u16* __restrict__ qkv, const float* __restrict__ bias_table,
    u16* __restrict__ out)
{
    __shared__ float ks[NWIN][DH];
    __shared__ float vs[NWIN][DH];
    __shared__ float sc[NWIN][NWIN + 1];
    __shared__ int lbl[NWIN];

    int widx = blockIdx.x;           // 0..511  (b*256 + wr*16 + wc)
    int head = blockIdx.y;           // 0..7
    int b  = widx >> 8;
    int w  = widx & 255;
    int wr = w >> 4, wc = w & 15;
    int n = threadIdx.x;             // 0..63  token in window
    int r = n >> 3, c = n & 7;
    int i = wr * WINSZ + r;          // coords in shifted image (== mask coords)
    int j = wc * WINSZ + c;
    int si = (i + 4) & 127;          // coords in original image
    int sj = (j + 4) & 127;
    size_t tok = (size_t)b * LTOK + (size_t)si * HW + sj;
    const u16* qp = qkv + tok * 768 + head * DH;

    const float SCALE = 0.17677669529663687f;  // 1/sqrt(32)
    float qreg[DH];
    #pragma unroll
    for (int d0 = 0; d0 < DH; d0 += 4) {
        float4 t = ld4(&qp[d0]);
        qreg[d0 + 0] = t.x * SCALE;
        qreg[d0 + 1] = t.y * SCALE;
        qreg[d0 + 2] = t.z * SCALE;
        qreg[d0 + 3] = t.w * SCALE;
    }
    #pragma unroll
    for (int d0 = 0; d0 < DH; d0 += 4) {
        float4 kk = ld4(&qp[256 + d0]);
        float4 vv = ld4(&qp[512 + d0]);
        *(float4*)&ks[n][d0] = kk;
        *(float4*)&vs[n][d0] = vv;
    }
    int li = (i < 120) ? 0 : (i < 124 ? 1 : 2);
    int lj = (j < 120) ? 0 : (j < 124 ? 1 : 2);
    lbl[n] = li * 3 + lj;
    __syncthreads();

    int myl = lbl[n];
    float mymax = -1e30f;
    for (int m = 0; m < NWIN; ++m) {
        float s = 0.f;
        #pragma unroll
        for (int d = 0; d < DH; ++d) s += qreg[d] * ks[m][d];
        int rm = m >> 3, cm = m & 7;
        int idx = (r - rm + 7) * 15 + (c - cm + 7);
        s += bias_table[idx * HEADS + head];
        if (lbl[m] != myl) s -= 100.f;
        sc[n][m] = s;
        mymax = fmaxf(mymax, s);
    }

    float oreg[DH];
    #pragma unroll
    for (int d = 0; d < DH; ++d) oreg[d] = 0.f;
    float sum = 0.f;
    for (int m = 0; m < NWIN; ++m) {
        float p = __expf(sc[n][m] - mymax);
        sum += p;
        #pragma unroll
        for (int d = 0; d < DH; ++d) oreg[d] += p * vs[m][d];
    }
    float inv = 1.f / sum;
    u16* op = out + tok * CDIM + head * DH;
    #pragma unroll
    for (int d0 = 0; d0 < DH; d0 += 4) {
        st4(&op[d0], make_float4(oreg[d0] * inv, oreg[d0 + 1] * inv,
                                 oreg[d0 + 2] * inv, oreg[d0 + 3] * inv));
    }
}

// ---------------------------------------------------------------------------
// Depthwise 3x3 conv (NHWC, SAME zero-pad) + bias + GELU. bf16 in/out.
// One block per pixel, thread t handles channels 4t..4t+3.
// ---------------------------------------------------------------------------
__global__ __launch_bounds__(256) void dwconv_kernel(
    const u16* __restrict__ h, const float* __restrict__ wgt,
    const float* __restrict__ bias, u16* __restrict__ out)
{
    int pix = blockIdx.x;            // b*16384 + i*128 + j
    int b  = pix >> 14;
    int ij = pix & 16383;
    int i = ij >> 7, j = ij & 127;
    int ch = threadIdx.x * 4;

    float wreg[4][9];
    #pragma unroll
    for (int q = 0; q < 4; ++q)
        #pragma unroll
        for (int t = 0; t < 9; ++t) wreg[q][t] = wgt[(ch + q) * 9 + t];

    float acc0 = 0.f, acc1 = 0.f, acc2 = 0.f, acc3 = 0.f;
    #pragma unroll
    for (int di = 0; di < 3; ++di) {
        int ii = i + di - 1;
        if (ii < 0 || ii >= HW) continue;
        #pragma unroll
        for (int dj = 0; dj < 3; ++dj) {
            int jj = j + dj - 1;
            if (jj < 0 || jj >= HW) continue;
            float4 v = ld4(&h[((size_t)b * LTOK + (size_t)ii * HW + jj) * HID + ch]);
            int t = di * 3 + dj;
            acc0 += v.x * wreg[0][t];
            acc1 += v.y * wreg[1][t];
            acc2 += v.z * wreg[2][t];
            acc3 += v.w * wreg[3][t];
        }
    }
    float4 bv = *(const float4*)&bias[ch];
    st4(&out[((size_t)b * LTOK + (size_t)i * HW + j) * HID + ch],
        make_float4(gelu_f(acc0 + bv.x), gelu_f(acc1 + bv.y),
                    gelu_f(acc2 + bv.z), gelu_f(acc3 + bv.w)));
}

// ---------------------------------------------------------------------------
extern "C" void kernel_launch(void* const* d_in, const int* in_sizes, int n_in,
                              void* d_out, int out_size, void* d_ws, size_t ws_size,
                              hipStream_t stream) {
    const float* x      = (const float*)d_in[0];
    const float* n1g    = (const float*)d_in[1];
    const float* n1b    = (const float*)d_in[2];
    const float* qkv_w  = (const float*)d_in[3];
    const float* qkv_b  = (const float*)d_in[4];
    const float* relb   = (const float*)d_in[5];
    const float* proj_w = (const float*)d_in[6];
    const float* proj_b = (const float*)d_in[7];
    const float* n2g    = (const float*)d_in[8];
    const float* n2b    = (const float*)d_in[9];
    const float* lin1_w = (const float*)d_in[10];
    const float* lin1_b = (const float*)d_in[11];
    const float* dw_w   = (const float*)d_in[12];
    const float* dw_b   = (const float*)d_in[13];
    const float* lin2_w = (const float*)d_in[14];
    const float* lin2_b = (const float*)d_in[15];
    float* out = (float*)d_out;

    // bf16 arena, 72M elems = 144 MB total with aliasing:
    //  [0,8M)   yn -> attn -> yn2 -> (start of h2)
    //  [8M,32M) qkv -> (rest of h2)
    //  [32M,40M) x1   (live step4..step8)
    //  [40M,72M) hbuf (live step6..step7)
    u16* ws16 = (u16*)d_ws;
    const size_t M8 = (size_t)MTOK * CDIM;   // 8,388,608
    u16* yn   = ws16;
    u16* qkv  = ws16 + M8;
    u16* attn = ws16;
    u16* x1   = ws16 + 4 * M8;
    u16* yn2  = ws16;
    u16* hbuf = ws16 + 5 * M8;
    u16* h2   = ws16;

    // 1) LN1: fp32 in, bf16 out
    ln_kernel<float, u16><<<MTOK / 4, 256, 0, stream>>>(x, n1g, n1b, yn);
    // 2) qkv = yn @ qkv_w + qkv_b
    gemm_kernel<0, u16, float, u16><<<dim3(768 / 64, MTOK / 64), 256, 0, stream>>>(
        yn, qkv_w, qkv_b, (const float*)nullptr, qkv, 768, CDIM);
    // 3) windowed attention
    attn_kernel<<<dim3(512, HEADS), 64, 0, stream>>>(qkv, relb, attn);
    // 4) x1 = attn @ proj_w + proj_b + x
    gemm_kernel<1, u16, float, u16><<<dim3(CDIM / 64, MTOK / 64), 256, 0, stream>>>(
        attn, proj_w, proj_b, x, x1, CDIM, CDIM);
    // 5) LN2: bf16 in, bf16 out
    ln_kernel<u16, u16><<<MTOK / 4, 256, 0, stream>>>(x1, n2g, n2b, yn2);
    // 6) hbuf = gelu(yn2 @ lin1_w + lin1_b)
    gemm_kernel<2, u16, float, u16><<<dim3(HID / 64, MTOK / 64), 256, 0, stream>>>(
        yn2, lin1_w, lin1_b, (const float*)nullptr, hbuf, HID, CDIM);
    // 7) h2 = gelu(dwconv3x3(hbuf) + dw_b)
    dwconv_kernel<<<MTOK, 256, 0, stream>>>(hbuf, dw_w, dw_b, h2);
    // 8) out = h2 @ lin2_w + lin2_b + x1   (fp32 out)
    gemm_kernel<1, u16, u16, float><<<dim3(CDIM / 64, MTOK / 64), 256, 0, stream>>>(
        h2, lin2_w, lin2_b, x1, out, CDIM, HID);

    (void)in_sizes; (void)n_in; (void)out_size; (void)ws_size;
}

// Round 3
// 380.597 us; speedup vs baseline: 2.5605x; 2.5605x over previous
//
#include <hip/hip_runtime.h>
#include <math.h>

// Problem constants
#define BATCH 2
#define HW 128          // H == W
#define CDIM 256
#define LTOK 16384      // HW*HW
#define MTOK 32768      // BATCH*LTOK
#define HEADS 8
#define DH 32
#define WINSZ 8
#define NWIN 64         // tokens per window
#define HID 1024

typedef unsigned int  u32;
typedef unsigned short u16;   // bf16 storage

typedef __attribute__((ext_vector_type(8))) short bf16x8;
typedef __attribute__((ext_vector_type(4))) float f32x4;

__device__ __forceinline__ float gelu_f(float v) {
    return 0.5f * v * (1.f + erff(v * 0.70710678118654752f));
}

__device__ __forceinline__ u16 f2bf(float f) {
    u32 u = __float_as_uint(f);
    u32 r = (u + 0x7fffu + ((u >> 16) & 1u)) >> 16;   // round-to-nearest-even
    return (u16)r;
}

// ---- generic 4-wide load/store: fp32 or bf16 ------------------------------
__device__ __forceinline__ float4 ld4(const float* p) { return *(const float4*)p; }
__device__ __forceinline__ float4 ld4(const u16* p) {
    uint2 v = *(const uint2*)p;
    float4 r;
    r.x = __uint_as_float((v.x & 0xffffu) << 16);
    r.y = __uint_as_float(v.x & 0xffff0000u);
    r.z = __uint_as_float((v.y & 0xffffu) << 16);
    r.w = __uint_as_float(v.y & 0xffff0000u);
    return r;
}
__device__ __forceinline__ void st4(float* p, float4 v) { *(float4*)p = v; }
__device__ __forceinline__ void st4(u16* p, float4 v) {
    uint2 o;
    o.x = (u32)f2bf(v.x) | ((u32)f2bf(v.y) << 16);
    o.y = (u32)f2bf(v.z) | ((u32)f2bf(v.w) << 16);
    *(uint2*)p = o;
}
// ---- scalar load/store ----------------------------------------------------
__device__ __forceinline__ float lds1(const float* p) { return *p; }
__device__ __forceinline__ float lds1(const u16* p) { return __uint_as_float(((u32)*p) << 16); }
__device__ __forceinline__ void sts1(float* p, float v) { *p = v; }
__device__ __forceinline__ void sts1(u16* p, float v) { *p = f2bf(v); }

// async global->LDS, 16B per lane (dest = wave-uniform base + lane*16)
__device__ __forceinline__ void glds16(const u16* g, u16* l) {
    __builtin_amdgcn_global_load_lds(
        (const __attribute__((address_space(1))) unsigned int*)g,
        (__attribute__((address_space(3))) unsigned int*)l, 16, 0, 0);
}

// ---------------------------------------------------------------------------
// Weight prep: fp32 [K][N] -> bf16 [N][K] (tiled LDS transpose, 32x32)
// ---------------------------------------------------------------------------
__global__ __launch_bounds__(256) void transpose_bf16_kernel(
    const float* __restrict__ in, u16* __restrict__ out, int K, int N)
{
    __shared__ float t[32][33];
    int bn = blockIdx.x * 32, bk = blockIdx.y * 32;
    int tx = threadIdx.x & 31, ty = threadIdx.x >> 5;   // 32 x 8
    #pragma unroll
    for (int i = 0; i < 32; i += 8)
        t[ty + i][tx] = in[(size_t)(bk + ty + i) * N + bn + tx];
    __syncthreads();
    #pragma unroll
    for (int i = 0; i < 32; i += 8)
        out[(size_t)(bn + ty + i) * K + bk + tx] = f2bf(t[tx][ty + i]);
}

// ---------------------------------------------------------------------------
// LayerNorm over C=256: one wave (64 lanes) per row, 4 rows per 256-thr block
// ---------------------------------------------------------------------------
template<typename TI, typename TO>
__global__ __launch_bounds__(256) void ln_kernel(
    const TI* __restrict__ x, const float* __restrict__ g,
    const float* __restrict__ b, TO* __restrict__ y)
{
    int wave = threadIdx.x >> 6;
    int lane = threadIdx.x & 63;
    int row = blockIdx.x * 4 + wave;
    const TI* xr = x + (size_t)row * CDIM;
    float4 v = ld4(&xr[lane * 4]);
    float s  = v.x + v.y + v.z + v.w;
    float s2 = v.x*v.x + v.y*v.y + v.z*v.z + v.w*v.w;
    #pragma unroll
    for (int off = 32; off > 0; off >>= 1) {
        s  += __shfl_xor(s,  off);
        s2 += __shfl_xor(s2, off);
    }
    float mu   = s * (1.f / CDIM);
    float var  = s2 * (1.f / CDIM) - mu * mu;
    float rstd = rsqrtf(var + 1e-5f);
    float4 gv = *(const float4*)&g[lane * 4];
    float4 bv = *(const float4*)&b[lane * 4];
    float4 o;
    o.x = (v.x - mu) * rstd * gv.x + bv.x;
    o.y = (v.y - mu) * rstd * gv.y + bv.y;
    o.z = (v.z - mu) * rstd * gv.z + bv.z;
    o.w = (v.w - mu) * rstd * gv.w + bv.w;
    st4(&y[(size_t)row * CDIM + lane * 4], o);
}

// ---------------------------------------------------------------------------
// MFMA bf16 GEMM: C[M,N] = A[M,K](bf16) @ Bt[N,K](bf16)^T + bias (+res/+gelu)
// 128x128 tile, BK=32, 256 threads = 4 waves (2x2), each wave 64x64 via
// 4x4 fragments of mfma_f32_16x16x32_bf16. global_load_lds staging (m97).
// EPI: 0 = bias, 1 = bias + residual, 2 = bias + GELU
// ---------------------------------------------------------------------------
template<int EPI, typename TR, typename TO>
__global__ __launch_bounds__(256) void mgemm_kernel(
    const u16* __restrict__ A, const u16* __restrict__ Bt,
    const float* __restrict__ bias, const TR* __restrict__ res,
    TO* __restrict__ Cc, int N, int K)
{
    __shared__ u16 smem[8192];     // As[128][32] @0, Bs[128][32] @4096

    int tid  = threadIdx.x;
    int lane = tid & 63;
    int wave = tid >> 6;
    int wr = wave >> 1, wc = wave & 1;
    size_t bm = (size_t)blockIdx.y * 128;
    size_t bn = (size_t)blockIdx.x * 128;

    // staging source addresses (per lane): 16 rows per gload, 4 chunks/row
    int srow = wave * 32 + (lane >> 2);
    int scol = (lane & 3) * 8;
    const u16* ga = A  + (bm + srow) * K + scol;
    const u16* gb = Bt + (bn + srow) * K + scol;
    u16* laA0 = &smem[wave * 1024];
    u16* laA1 = &smem[wave * 1024 + 512];
    u16* laB0 = &smem[4096 + wave * 1024];
    u16* laB1 = &smem[4096 + wave * 1024 + 512];

    // fragment read offsets
    int ar = wr * 64 + (lane & 15);
    int br = wc * 64 + (lane & 15);
    int kc = (lane >> 4) * 8;

    f32x4 acc[4][4] = {};

    for (int kt = 0; kt < K; kt += 32) {
        glds16(ga, laA0);
        glds16(ga + 16 * K, laA1);
        glds16(gb, laB0);
        glds16(gb + 16 * K, laB1);
        ga += 32; gb += 32;
        __syncthreads();

        bf16x8 af[4], bfv[4];
        #pragma unroll
        for (int m = 0; m < 4; ++m)
            af[m] = *(const bf16x8*)&smem[(ar + m * 16) * 32 + kc];
        #pragma unroll
        for (int n = 0; n < 4; ++n)
            bfv[n] = *(const bf16x8*)&smem[4096 + (br + n * 16) * 32 + kc];
        #pragma unroll
        for (int m = 0; m < 4; ++m)
            #pragma unroll
            for (int n = 0; n < 4; ++n)
                acc[m][n] = __builtin_amdgcn_mfma_f32_16x16x32_bf16(
                    af[m], bfv[n], acc[m][n], 0, 0, 0);
        __syncthreads();
    }

    // epilogue: row = bm+wr*64+m*16+(lane>>4)*4+r, col = bn+wc*64+n*16+(lane&15)
    int colb = (int)bn + wc * 64 + (lane & 15);
    int rowb = (int)bm + wr * 64 + (lane >> 4) * 4;
    #pragma unroll
    for (int n = 0; n < 4; ++n) {
        float bv = bias[colb + n * 16];
        #pragma unroll
        for (int m = 0; m < 4; ++m) {
            #pragma unroll
            for (int r = 0; r < 4; ++r) {
                int row = rowb + m * 16 + r;
                float v = acc[m][n][r] + bv;
                if (EPI == 1) v += lds1(&res[(size_t)row * N + colb + n * 16]);
                if (EPI == 2) v = gelu_f(v);
                sts1(&Cc[(size_t)row * N + colb + n * 16], v);
            }
        }
    }
}

// ---------------------------------------------------------------------------
// Windowed attention, one 64-thread block per (window, head).
// ---------------------------------------------------------------------------
__global__ __launch_bounds__(64) void attn_kernel(
    const u16* __restrict__ qkv, const float* __restrict__ bias_table,
    u16* __restrict__ out)
{
    __shared__ float ks[NWIN][DH];
    __shared__ float vs[NWIN][DH];
    __shared__ float sc[NWIN][NWIN + 1];
    __shared__ int lbl[NWIN];

    int widx = blockIdx.x;           // 0..511  (b*256 + wr*16 + wc)
    int head = blockIdx.y;           // 0..7
    int b  = widx >> 8;
    int w  = widx & 255;
    int wr = w >> 4, wc = w & 15;
    int n = threadIdx.x;             // 0..63  token in window
    int r = n >> 3, c = n & 7;
    int i = wr * WINSZ + r;          // coords in shifted image (== mask coords)
    int j = wc * WINSZ + c;
    int si = (i + 4) & 127;          // coords in original image
    int sj = (j + 4) & 127;
    size_t tok = (size_t)b * LTOK + (size_t)si * HW + sj;
    const u16* qp = qkv + tok * 768 + head * DH;

    const float SCALE = 0.17677669529663687f;  // 1/sqrt(32)
    float qreg[DH];
    #pragma unroll
    for (int d0 = 0; d0 < DH; d0 += 4) {
        float4 t = ld4(&qp[d0]);
        qreg[d0 + 0] = t.x * SCALE;
        qreg[d0 + 1] = t.y * SCALE;
        qreg[d0 + 2] = t.z * SCALE;
        qreg[d0 + 3] = t.w * SCALE;
    }
    #pragma unroll
    for (int d0 = 0; d0 < DH; d0 += 4) {
        float4 kk = ld4(&qp[256 + d0]);
        float4 vv = ld4(&qp[512 + d0]);
        *(float4*)&ks[n][d0] = kk;
        *(float4*)&vs[n][d0] = vv;
    }
    int li = (i < 120) ? 0 : (i < 124 ? 1 : 2);
    int lj = (j < 120) ? 0 : (j < 124 ? 1 : 2);
    lbl[n] = li * 3 + lj;
    __syncthreads();

    int myl = lbl[n];
    float mymax = -1e30f;
    for (int m = 0; m < NWIN; ++m) {
        float s = 0.f;
        #pragma unroll
        for (int d = 0; d < DH; ++d) s += qreg[d] * ks[m][d];
        int rm = m >> 3, cm = m & 7;
        int idx = (r - rm + 7) * 15 + (c - cm + 7);
        s += bias_table[idx * HEADS + head];
        if (lbl[m] != myl) s -= 100.f;
        sc[n][m] = s;
        mymax = fmaxf(mymax, s);
    }

    float oreg[DH];
    #pragma unroll
    for (int d = 0; d < DH; ++d) oreg[d] = 0.f;
    float sum = 0.f;
    for (int m = 0; m < NWIN; ++m) {
        float p = __expf(sc[n][m] - mymax);
        sum += p;
        #pragma unroll
        for (int d = 0; d < DH; ++d) oreg[d] += p * vs[m][d];
    }
    float inv = 1.f / sum;
    u16* op = out + tok * CDIM + head * DH;
    #pragma unroll
    for (int d0 = 0; d0 < DH; d0 += 4) {
        st4(&op[d0], make_float4(oreg[d0] * inv, oreg[d0 + 1] * inv,
                                 oreg[d0 + 2] * inv, oreg[d0 + 3] * inv));
    }
}

// ---------------------------------------------------------------------------
// Depthwise 3x3 conv (NHWC, SAME zero-pad) + bias + GELU. bf16 in/out.
// ---------------------------------------------------------------------------
__global__ __launch_bounds__(256) void dwconv_kernel(
    const u16* __restrict__ h, const float* __restrict__ wgt,
    const float* __restrict__ bias, u16* __restrict__ out)
{
    int pix = blockIdx.x;            // b*16384 + i*128 + j
    int b  = pix >> 14;
    int ij = pix & 16383;
    int i = ij >> 7, j = ij & 127;
    int ch = threadIdx.x * 4;

    float wreg[4][9];
    #pragma unroll
    for (int q = 0; q < 4; ++q)
        #pragma unroll
        for (int t = 0; t < 9; ++t) wreg[q][t] = wgt[(ch + q) * 9 + t];

    float acc0 = 0.f, acc1 = 0.f, acc2 = 0.f, acc3 = 0.f;
    #pragma unroll
    for (int di = 0; di < 3; ++di) {
        int ii = i + di - 1;
        if (ii < 0 || ii >= HW) continue;
        #pragma unroll
        for (int dj = 0; dj < 3; ++dj) {
            int jj = j + dj - 1;
            if (jj < 0 || jj >= HW) continue;
            float4 v = ld4(&h[((size_t)b * LTOK + (size_t)ii * HW + jj) * HID + ch]);
            int t = di * 3 + dj;
            acc0 += v.x * wreg[0][t];
            acc1 += v.y * wreg[1][t];
            acc2 += v.z * wreg[2][t];
            acc3 += v.w * wreg[3][t];
        }
    }
    float4 bv = *(const float4*)&bias[ch];
    st4(&out[((size_t)b * LTOK + (size_t)i * HW + j) * HID + ch],
        make_float4(gelu_f(acc0 + bv.x), gelu_f(acc1 + bv.y),
                    gelu_f(acc2 + bv.z), gelu_f(acc3 + bv.w)));
}

// ---------------------------------------------------------------------------
extern "C" void kernel_launch(void* const* d_in, const int* in_sizes, int n_in,
                              void* d_out, int out_size, void* d_ws, size_t ws_size,
                              hipStream_t stream) {
    const float* x      = (const float*)d_in[0];
    const float* n1g    = (const float*)d_in[1];
    const float* n1b    = (const float*)d_in[2];
    const float* qkv_w  = (const float*)d_in[3];
    const float* qkv_b  = (const float*)d_in[4];
    const float* relb   = (const float*)d_in[5];
    const float* proj_w = (const float*)d_in[6];
    const float* proj_b = (const float*)d_in[7];
    const float* n2g    = (const float*)d_in[8];
    const float* n2b    = (const float*)d_in[9];
    const float* lin1_w = (const float*)d_in[10];
    const float* lin1_b = (const float*)d_in[11];
    const float* dw_w   = (const float*)d_in[12];
    const float* dw_b   = (const float*)d_in[13];
    const float* lin2_w = (const float*)d_in[14];
    const float* lin2_b = (const float*)d_in[15];
    float* out = (float*)d_out;

    // bf16 arena, 72M elems = 144 MB (same as passing round 2):
    //  R0 [0,8M):   yn -> attn -> yn2 -> h2[0:8M)
    //  R1 [8M,32M): qkv -> lin1_wt (after attn) -> h2[8M:32M)
    //  R2 [32M,40M): x1 (steps 4-8)
    //  R3 [40M,72M): qkv_wt+proj_wt (steps 0-4) -> hbuf (6-7) -> lin2_wt (8)
    u16* ws16 = (u16*)d_ws;
    const size_t M8 = (size_t)MTOK * CDIM;   // 8,388,608
    u16* yn      = ws16;
    u16* qkv     = ws16 + M8;
    u16* attn    = ws16;
    u16* x1      = ws16 + 4 * M8;
    u16* yn2     = ws16;
    u16* hbuf    = ws16 + 5 * M8;
    u16* h2      = ws16;
    u16* qkv_wt  = ws16 + 5 * M8;            // [768][256]
    u16* proj_wt = qkv_wt + 768 * 256;       // [256][256]
    u16* lin1_wt = ws16 + M8;                // [1024][256]
    u16* lin2_wt = ws16 + 5 * M8;            // [256][1024]

    // 0) weight prep (qkv, proj)
    transpose_bf16_kernel<<<dim3(768 / 32, 256 / 32), 256, 0, stream>>>(qkv_w, qkv_wt, 256, 768);
    transpose_bf16_kernel<<<dim3(256 / 32, 256 / 32), 256, 0, stream>>>(proj_w, proj_wt, 256, 256);
    // 1) LN1: fp32 in, bf16 out
    ln_kernel<float, u16><<<MTOK / 4, 256, 0, stream>>>(x, n1g, n1b, yn);
    // 2) qkv = yn @ qkv_w + qkv_b
    mgemm_kernel<0, float, u16><<<dim3(768 / 128, MTOK / 128), 256, 0, stream>>>(
        yn, qkv_wt, qkv_b, (const float*)nullptr, qkv, 768, CDIM);
    // 3) windowed attention
    attn_kernel<<<dim3(512, HEADS), 64, 0, stream>>>(qkv, relb, attn);
    // weight prep (lin1) into R1 (qkv now dead)
    transpose_bf16_kernel<<<dim3(1024 / 32, 256 / 32), 256, 0, stream>>>(lin1_w, lin1_wt, 256, 1024);
    // 4) x1 = attn @ proj_w + proj_b + x
    mgemm_kernel<1, float, u16><<<dim3(CDIM / 128, MTOK / 128), 256, 0, stream>>>(
        attn, proj_wt, proj_b, x, x1, CDIM, CDIM);
    // 5) LN2: bf16 in, bf16 out
    ln_kernel<u16, u16><<<MTOK / 4, 256, 0, stream>>>(x1, n2g, n2b, yn2);
    // 6) hbuf = gelu(yn2 @ lin1_w + lin1_b)
    mgemm_kernel<2, float, u16><<<dim3(HID / 128, MTOK / 128), 256, 0, stream>>>(
        yn2, lin1_wt, lin1_b, (const float*)nullptr, hbuf, HID, CDIM);
    // 7) h2 = gelu(dwconv3x3(hbuf) + dw_b)
    dwconv_kernel<<<MTOK, 256, 0, stream>>>(hbuf, dw_w, dw_b, h2);
    // weight prep (lin2) into R3 (hbuf now dead)
    transpose_bf16_kernel<<<dim3(256 / 32, 1024 / 32), 256, 0, stream>>>(lin2_w, lin2_wt, 1024, 256);
    // 8) out = h2 @ lin2_w + lin2_b + x1   (fp32 out)
    mgemm_kernel<1, u16, float><<<dim3(CDIM / 128, MTOK / 128), 256, 0, stream>>>(
        h2, lin2_wt, lin2_b, x1, out, CDIM, HID);

    (void)in_sizes; (void)n_in; (void)out_size; (void)ws_size;
}

// Round 4
// 312.713 us; speedup vs baseline: 3.1164x; 1.2171x over previous
//
#include <hip/hip_runtime.h>
#include <math.h>

// Problem constants
#define BATCH 2
#define HW 128          // H == W
#define CDIM 256
#define LTOK 16384      // HW*HW
#define MTOK 32768      // BATCH*LTOK
#define HEADS 8
#define DH 32
#define WINSZ 8
#define NWIN 64         // tokens per window
#define HID 1024

typedef unsigned int  u32;
typedef unsigned short u16;   // bf16 storage

typedef __attribute__((ext_vector_type(8))) short bf16x8;
typedef __attribute__((ext_vector_type(4))) float f32x4;

__device__ __forceinline__ float gelu_f(float v) {
    return 0.5f * v * (1.f + erff(v * 0.70710678118654752f));
}

__device__ __forceinline__ u16 f2bf(float f) {
    u32 u = __float_as_uint(f);
    u32 r = (u + 0x7fffu + ((u >> 16) & 1u)) >> 16;   // round-to-nearest-even
    return (u16)r;
}

// ---- generic 4-wide load/store: fp32 or bf16 ------------------------------
__device__ __forceinline__ float4 ld4(const float* p) { return *(const float4*)p; }
__device__ __forceinline__ float4 ld4(const u16* p) {
    uint2 v = *(const uint2*)p;
    float4 r;
    r.x = __uint_as_float((v.x & 0xffffu) << 16);
    r.y = __uint_as_float(v.x & 0xffff0000u);
    r.z = __uint_as_float((v.y & 0xffffu) << 16);
    r.w = __uint_as_float(v.y & 0xffff0000u);
    return r;
}
__device__ __forceinline__ void st4(float* p, float4 v) { *(float4*)p = v; }
__device__ __forceinline__ void st4(u16* p, float4 v) {
    uint2 o;
    o.x = (u32)f2bf(v.x) | ((u32)f2bf(v.y) << 16);
    o.y = (u32)f2bf(v.z) | ((u32)f2bf(v.w) << 16);
    *(uint2*)p = o;
}
// ---- scalar load/store ----------------------------------------------------
__device__ __forceinline__ float lds1(const float* p) { return *p; }
__device__ __forceinline__ float lds1(const u16* p) { return __uint_as_float(((u32)*p) << 16); }
__device__ __forceinline__ void sts1(float* p, float v) { *p = v; }
__device__ __forceinline__ void sts1(u16* p, float v) { *p = f2bf(v); }

// ---- 8-wide bf16 load -> 8 floats -----------------------------------------
__device__ __forceinline__ void ld8bf(const u16* p, float* v) {
    uint4 r = *(const uint4*)p;
    v[0] = __uint_as_float((r.x & 0xffffu) << 16);
    v[1] = __uint_as_float(r.x & 0xffff0000u);
    v[2] = __uint_as_float((r.y & 0xffffu) << 16);
    v[3] = __uint_as_float(r.y & 0xffff0000u);
    v[4] = __uint_as_float((r.z & 0xffffu) << 16);
    v[5] = __uint_as_float(r.z & 0xffff0000u);
    v[6] = __uint_as_float((r.w & 0xffffu) << 16);
    v[7] = __uint_as_float(r.w & 0xffff0000u);
}

// async global->LDS, 16B per lane (dest = wave-uniform base + lane*16)
__device__ __forceinline__ void glds16(const u16* g, u16* l) {
    __builtin_amdgcn_global_load_lds(
        (const __attribute__((address_space(1))) unsigned int*)g,
        (__attribute__((address_space(3))) unsigned int*)l, 16, 0, 0);
}

// ---------------------------------------------------------------------------
// Weight prep: fp32 [K][N] -> bf16 [N][K] (tiled LDS transpose, 32x32)
// ---------------------------------------------------------------------------
__global__ __launch_bounds__(256) void transpose_bf16_kernel(
    const float* __restrict__ in, u16* __restrict__ out, int K, int N)
{
    __shared__ float t[32][33];
    int bn = blockIdx.x * 32, bk = blockIdx.y * 32;
    int tx = threadIdx.x & 31, ty = threadIdx.x >> 5;   // 32 x 8
    #pragma unroll
    for (int i = 0; i < 32; i += 8)
        t[ty + i][tx] = in[(size_t)(bk + ty + i) * N + bn + tx];
    __syncthreads();
    #pragma unroll
    for (int i = 0; i < 32; i += 8)
        out[(size_t)(bn + ty + i) * K + bk + tx] = f2bf(t[tx][ty + i]);
}

// ---------------------------------------------------------------------------
// dw weight prep: [1024][9] fp32 -> [9][1024] fp32 (into d_out scratch)
// ---------------------------------------------------------------------------
__global__ __launch_bounds__(256) void dwprep_kernel(
    const float* __restrict__ in, float* __restrict__ out)
{
    int idx = blockIdx.x * 256 + threadIdx.x;   // 0..9215
    if (idx < 9 * HID) {
        int ch = idx / 9, t = idx - ch * 9;
        out[t * HID + ch] = in[idx];
    }
}

// ---------------------------------------------------------------------------
// LayerNorm over C=256: one wave (64 lanes) per row, 4 rows per 256-thr block
// ---------------------------------------------------------------------------
template<typename TI, typename TO>
__global__ __launch_bounds__(256) void ln_kernel(
    const TI* __restrict__ x, const float* __restrict__ g,
    const float* __restrict__ b, TO* __restrict__ y)
{
    int wave = threadIdx.x >> 6;
    int lane = threadIdx.x & 63;
    int row = blockIdx.x * 4 + wave;
    const TI* xr = x + (size_t)row * CDIM;
    float4 v = ld4(&xr[lane * 4]);
    float s  = v.x + v.y + v.z + v.w;
    float s2 = v.x*v.x + v.y*v.y + v.z*v.z + v.w*v.w;
    #pragma unroll
    for (int off = 32; off > 0; off >>= 1) {
        s  += __shfl_xor(s,  off);
        s2 += __shfl_xor(s2, off);
    }
    float mu   = s * (1.f / CDIM);
    float var  = s2 * (1.f / CDIM) - mu * mu;
    float rstd = rsqrtf(var + 1e-5f);
    float4 gv = *(const float4*)&g[lane * 4];
    float4 bv = *(const float4*)&b[lane * 4];
    float4 o;
    o.x = (v.x - mu) * rstd * gv.x + bv.x;
    o.y = (v.y - mu) * rstd * gv.y + bv.y;
    o.z = (v.z - mu) * rstd * gv.z + bv.z;
    o.w = (v.w - mu) * rstd * gv.w + bv.w;
    st4(&y[(size_t)row * CDIM + lane * 4], o);
}

// ---------------------------------------------------------------------------
// MFMA bf16 GEMM: C[M,N] = A[M,K](bf16) @ Bt[N,K](bf16)^T + bias (+res/+gelu)
// 128x128 tile, BK=32, 256 threads = 4 waves (2x2), each wave 64x64 via
// 4x4 fragments of mfma_f32_16x16x32_bf16. global_load_lds staging (m97).
// EPI: 0 = bias, 1 = bias + residual, 2 = bias + GELU
// ---------------------------------------------------------------------------
template<int EPI, typename TR, typename TO>
__global__ __launch_bounds__(256) void mgemm_kernel(
    const u16* __restrict__ A, const u16* __restrict__ Bt,
    const float* __restrict__ bias, const TR* __restrict__ res,
    TO* __restrict__ Cc, int N, int K)
{
    __shared__ u16 smem[8192];     // As[128][32] @0, Bs[128][32] @4096

    int tid  = threadIdx.x;
    int lane = tid & 63;
    int wave = tid >> 6;
    int wr = wave >> 1, wc = wave & 1;
    size_t bm = (size_t)blockIdx.y * 128;
    size_t bn = (size_t)blockIdx.x * 128;

    // staging source addresses (per lane): 16 rows per gload, 4 chunks/row
    int srow = wave * 32 + (lane >> 2);
    int scol = (lane & 3) * 8;
    const u16* ga = A  + (bm + srow) * K + scol;
    const u16* gb = Bt + (bn + srow) * K + scol;
    u16* laA0 = &smem[wave * 1024];
    u16* laA1 = &smem[wave * 1024 + 512];
    u16* laB0 = &smem[4096 + wave * 1024];
    u16* laB1 = &smem[4096 + wave * 1024 + 512];

    // fragment read offsets
    int ar = wr * 64 + (lane & 15);
    int br = wc * 64 + (lane & 15);
    int kc = (lane >> 4) * 8;

    f32x4 acc[4][4] = {};

    for (int kt = 0; kt < K; kt += 32) {
        glds16(ga, laA0);
        glds16(ga + 16 * K, laA1);
        glds16(gb, laB0);
        glds16(gb + 16 * K, laB1);
        ga += 32; gb += 32;
        __syncthreads();

        bf16x8 af[4], bfv[4];
        #pragma unroll
        for (int m = 0; m < 4; ++m)
            af[m] = *(const bf16x8*)&smem[(ar + m * 16) * 32 + kc];
        #pragma unroll
        for (int n = 0; n < 4; ++n)
            bfv[n] = *(const bf16x8*)&smem[4096 + (br + n * 16) * 32 + kc];
        #pragma unroll
        for (int m = 0; m < 4; ++m)
            #pragma unroll
            for (int n = 0; n < 4; ++n)
                acc[m][n] = __builtin_amdgcn_mfma_f32_16x16x32_bf16(
                    af[m], bfv[n], acc[m][n], 0, 0, 0);
        __syncthreads();
    }

    // epilogue: row = bm+wr*64+m*16+(lane>>4)*4+r, col = bn+wc*64+n*16+(lane&15)
    int colb = (int)bn + wc * 64 + (lane & 15);
    int rowb = (int)bm + wr * 64 + (lane >> 4) * 4;
    #pragma unroll
    for (int n = 0; n < 4; ++n) {
        float bv = bias[colb + n * 16];
        #pragma unroll
        for (int m = 0; m < 4; ++m) {
            #pragma unroll
            for (int r = 0; r < 4; ++r) {
                int row = rowb + m * 16 + r;
                float v = acc[m][n][r] + bv;
                if (EPI == 1) v += lds1(&res[(size_t)row * N + colb + n * 16]);
                if (EPI == 2) v = gelu_f(v);
                sts1(&Cc[(size_t)row * N + colb + n * 16], v);
            }
        }
    }
}

// ---------------------------------------------------------------------------
// Windowed attention, one 64-thread block per (window, head).
// ---------------------------------------------------------------------------
__global__ __launch_bounds__(64) void attn_kernel(
    const u16* __restrict__ qkv, const float* __restrict__ bias_table,
    u16* __restrict__ out)
{
    __shared__ float ks[NWIN][DH];
    __shared__ float vs[NWIN][DH];
    __shared__ float sc[NWIN][NWIN + 1];
    __shared__ int lbl[NWIN];

    int widx = blockIdx.x;           // 0..511  (b*256 + wr*16 + wc)
    int head = blockIdx.y;           // 0..7
    int b  = widx >> 8;
    int w  = widx & 255;
    int wr = w >> 4, wc = w & 15;
    int n = threadIdx.x;             // 0..63  token in window
    int r = n >> 3, c = n & 7;
    int i = wr * WINSZ + r;          // coords in shifted image (== mask coords)
    int j = wc * WINSZ + c;
    int si = (i + 4) & 127;          // coords in original image
    int sj = (j + 4) & 127;
    size_t tok = (size_t)b * LTOK + (size_t)si * HW + sj;
    const u16* qp = qkv + tok * 768 + head * DH;

    const float SCALE = 0.17677669529663687f;  // 1/sqrt(32)
    float qreg[DH];
    #pragma unroll
    for (int d0 = 0; d0 < DH; d0 += 4) {
        float4 t = ld4(&qp[d0]);
        qreg[d0 + 0] = t.x * SCALE;
        qreg[d0 + 1] = t.y * SCALE;
        qreg[d0 + 2] = t.z * SCALE;
        qreg[d0 + 3] = t.w * SCALE;
    }
    #pragma unroll
    for (int d0 = 0; d0 < DH; d0 += 4) {
        float4 kk = ld4(&qp[256 + d0]);
        float4 vv = ld4(&qp[512 + d0]);
        *(float4*)&ks[n][d0] = kk;
        *(float4*)&vs[n][d0] = vv;
    }
    int li = (i < 120) ? 0 : (i < 124 ? 1 : 2);
    int lj = (j < 120) ? 0 : (j < 124 ? 1 : 2);
    lbl[n] = li * 3 + lj;
    __syncthreads();

    int myl = lbl[n];
    float mymax = -1e30f;
    for (int m = 0; m < NWIN; ++m) {
        float s = 0.f;
        #pragma unroll
        for (int d = 0; d < DH; ++d) s += qreg[d] * ks[m][d];
        int rm = m >> 3, cm = m & 7;
        int idx = (r - rm + 7) * 15 + (c - cm + 7);
        s += bias_table[idx * HEADS + head];
        if (lbl[m] != myl) s -= 100.f;
        sc[n][m] = s;
        mymax = fmaxf(mymax, s);
    }

    float oreg[DH];
    #pragma unroll
    for (int d = 0; d < DH; ++d) oreg[d] = 0.f;
    float sum = 0.f;
    for (int m = 0; m < NWIN; ++m) {
        float p = __expf(sc[n][m] - mymax);
        sum += p;
        #pragma unroll
        for (int d = 0; d < DH; ++d) oreg[d] += p * vs[m][d];
    }
    float inv = 1.f / sum;
    u16* op = out + tok * CDIM + head * DH;
    #pragma unroll
    for (int d0 = 0; d0 < DH; d0 += 4) {
        st4(&op[d0], make_float4(oreg[d0] * inv, oreg[d0 + 1] * inv,
                                 oreg[d0 + 2] * inv, oreg[d0 + 3] * inv));
    }
}

// ---------------------------------------------------------------------------
// Depthwise 3x3 conv (NHWC, SAME zero-pad) + bias + GELU. bf16 in/out.
// Thread: 8 channels x 4 consecutive pixels along j (16B loads, j-overlap
// reuse: 18 row-loads for 4 outputs). Block: 8 pixels x 1024 ch. Grid 4096.
// wt9: [9][1024] fp32 tap-major table (pre-transposed, lives in d_out scratch)
// ---------------------------------------------------------------------------
__global__ __launch_bounds__(256) void dwconv_kernel(
    const u16* __restrict__ h, const float* __restrict__ wt9,
    const float* __restrict__ bias, u16* __restrict__ out)
{
    int blk = blockIdx.x;             // b*2048 + i*16 + jt
    int b   = blk >> 11;
    int rem = blk & 2047;
    int i   = rem >> 4;
    int jt  = rem & 15;
    int cg  = (threadIdx.x & 127) * 8;           // channel base (0..1016)
    int j0  = jt * 8 + (threadIdx.x >> 7) * 4;   // first of 4 output pixels

    float acc[4][8] = {};
    const u16* base = h + (size_t)b * LTOK * HID + cg;

    #pragma unroll
    for (int di = 0; di < 3; ++di) {
        int ii = i + di - 1;
        if (ii < 0 || ii >= HW) continue;
        const u16* rowp = base + (size_t)ii * HW * HID;
        float v[6][8];
        #pragma unroll
        for (int cc = 0; cc < 6; ++cc) {
            int jj = j0 - 1 + cc;
            if (jj >= 0 && jj < HW) {
                ld8bf(&rowp[(size_t)jj * HID], v[cc]);
            } else {
                #pragma unroll
                for (int q = 0; q < 8; ++q) v[cc][q] = 0.f;
            }
        }
        #pragma unroll
        for (int t = 0; t < 3; ++t) {
            const float* wp = &wt9[(di * 3 + t) * HID + cg];
            float4 wa = *(const float4*)wp;
            float4 wb = *(const float4*)(wp + 4);
            float w[8] = {wa.x, wa.y, wa.z, wa.w, wb.x, wb.y, wb.z, wb.w};
            #pragma unroll
            for (int p = 0; p < 4; ++p)
                #pragma unroll
                for (int q = 0; q < 8; ++q)
                    acc[p][q] += v[p + t][q] * w[q];
        }
    }

    float4 ba = *(const float4*)&bias[cg];
    float4 bb = *(const float4*)&bias[cg + 4];
    float bs[8] = {ba.x, ba.y, ba.z, ba.w, bb.x, bb.y, bb.z, bb.w};
    u16* ob = out + ((size_t)b * LTOK + (size_t)i * HW + j0) * HID + cg;
    #pragma unroll
    for (int p = 0; p < 4; ++p) {
        u32 o[4];
        #pragma unroll
        for (int q = 0; q < 4; ++q) {
            u16 lo = f2bf(gelu_f(acc[p][2 * q] + bs[2 * q]));
            u16 hi = f2bf(gelu_f(acc[p][2 * q + 1] + bs[2 * q + 1]));
            o[q] = (u32)lo | ((u32)hi << 16);
        }
        *(uint4*)(ob + (size_t)p * HID) = make_uint4(o[0], o[1], o[2], o[3]);
    }
}

// ---------------------------------------------------------------------------
extern "C" void kernel_launch(void* const* d_in, const int* in_sizes, int n_in,
                              void* d_out, int out_size, void* d_ws, size_t ws_size,
                              hipStream_t stream) {
    const float* x      = (const float*)d_in[0];
    const float* n1g    = (const float*)d_in[1];
    const float* n1b    = (const float*)d_in[2];
    const float* qkv_w  = (const float*)d_in[3];
    const float* qkv_b  = (const float*)d_in[4];
    const float* relb   = (const float*)d_in[5];
    const float* proj_w = (const float*)d_in[6];
    const float* proj_b = (const float*)d_in[7];
    const float* n2g    = (const float*)d_in[8];
    const float* n2b    = (const float*)d_in[9];
    const float* lin1_w = (const float*)d_in[10];
    const float* lin1_b = (const float*)d_in[11];
    const float* dw_w   = (const float*)d_in[12];
    const float* dw_b   = (const float*)d_in[13];
    const float* lin2_w = (const float*)d_in[14];
    const float* lin2_b = (const float*)d_in[15];
    float* out = (float*)d_out;

    // bf16 arena (9*M8 elems = 151 MB, same as passing round 3):
    //  R0 [0,4M8):   yn -> qkv(part) ... h2[0:4M8)
    //  R2 [4M8,5M8): x1 (steps 4-8)
    //  R3 [5M8,9M8): qkv_wt+proj_wt (steps 0-4) -> hbuf (6-7) -> lin2_wt (8)
    u16* ws16 = (u16*)d_ws;
    const size_t M8 = (size_t)MTOK * CDIM;   // 8,388,608
    u16* yn      = ws16;
    u16* qkv     = ws16 + M8;
    u16* attn    = ws16;
    u16* x1      = ws16 + 4 * M8;
    u16* yn2     = ws16;
    u16* hbuf    = ws16 + 5 * M8;
    u16* h2      = ws16;
    u16* qkv_wt  = ws16 + 5 * M8;            // [768][256]
    u16* proj_wt = qkv_wt + 768 * 256;       // [256][256]
    u16* lin1_wt = ws16 + M8;                // [1024][256]
    u16* lin2_wt = ws16 + 5 * M8;            // [256][1024]
    float* wt9   = (float*)d_out;            // [9][1024] scratch; d_out dead
                                             // until step 8 fully overwrites it

    // 0) weight prep (qkv, proj)
    transpose_bf16_kernel<<<dim3(768 / 32, 256 / 32), 256, 0, stream>>>(qkv_w, qkv_wt, 256, 768);
    transpose_bf16_kernel<<<dim3(256 / 32, 256 / 32), 256, 0, stream>>>(proj_w, proj_wt, 256, 256);
    // 1) LN1: fp32 in, bf16 out
    ln_kernel<float, u16><<<MTOK / 4, 256, 0, stream>>>(x, n1g, n1b, yn);
    // 2) qkv = yn @ qkv_w + qkv_b
    mgemm_kernel<0, float, u16><<<dim3(768 / 128, MTOK / 128), 256, 0, stream>>>(
        yn, qkv_wt, qkv_b, (const float*)nullptr, qkv, 768, CDIM);
    // 3) windowed attention
    attn_kernel<<<dim3(512, HEADS), 64, 0, stream>>>(qkv, relb, attn);
    // weight prep (lin1) into R1 (qkv now dead); dw weights into d_out scratch
    transpose_bf16_kernel<<<dim3(1024 / 32, 256 / 32), 256, 0, stream>>>(lin1_w, lin1_wt, 256, 1024);
    dwprep_kernel<<<36, 256, 0, stream>>>(dw_w, wt9);
    // 4) x1 = attn @ proj_w + proj_b + x
    mgemm_kernel<1, float, u16><<<dim3(CDIM / 128, MTOK / 128), 256, 0, stream>>>(
        attn, proj_wt, proj_b, x, x1, CDIM, CDIM);
    // 5) LN2: bf16 in, bf16 out
    ln_kernel<u16, u16><<<MTOK / 4, 256, 0, stream>>>(x1, n2g, n2b, yn2);
    // 6) hbuf = gelu(yn2 @ lin1_w + lin1_b)
    mgemm_kernel<2, float, u16><<<dim3(HID / 128, MTOK / 128), 256, 0, stream>>>(
        yn2, lin1_wt, lin1_b, (const float*)nullptr, hbuf, HID, CDIM);
    // 7) h2 = gelu(dwconv3x3(hbuf) + dw_b)
    dwconv_kernel<<<BATCH * 2048, 256, 0, stream>>>(hbuf, wt9, dw_b, h2);
    // weight prep (lin2) into R3 (hbuf now dead)
    transpose_bf16_kernel<<<dim3(256 / 32, 1024 / 32), 256, 0, stream>>>(lin2_w, lin2_wt, 1024, 256);
    // 8) out = h2 @ lin2_w + lin2_b + x1   (fp32 out)
    mgemm_kernel<1, u16, float><<<dim3(CDIM / 128, MTOK / 128), 256, 0, stream>>>(
        h2, lin2_wt, lin2_b, x1, out, CDIM, HID);

    (void)in_sizes; (void)n_in; (void)out_size; (void)ws_size;
}

// Round 5
// 300.699 us; speedup vs baseline: 3.2409x; 1.0400x over previous
//
#include <hip/hip_runtime.h>
#include <math.h>

// Problem constants
#define BATCH 2
#define HW 128          // H == W
#define CDIM 256
#define LTOK 16384      // HW*HW
#define MTOK 32768      // BATCH*LTOK
#define HEADS 8
#define DH 32
#define WINSZ 8
#define NWIN 64         // tokens per window
#define HID 1024

typedef unsigned int  u32;
typedef unsigned short u16;   // bf16 storage

typedef __attribute__((ext_vector_type(8))) short bf16x8;
typedef __attribute__((ext_vector_type(4))) float f32x4;

__device__ __forceinline__ float gelu_f(float v) {
    return 0.5f * v * (1.f + erff(v * 0.70710678118654752f));
}

__device__ __forceinline__ u16 f2bf(float f) {
    u32 u = __float_as_uint(f);
    u32 r = (u + 0x7fffu + ((u >> 16) & 1u)) >> 16;   // round-to-nearest-even
    return (u16)r;
}

// ---- generic 4-wide load/store: fp32 or bf16 ------------------------------
__device__ __forceinline__ float4 ld4(const float* p) { return *(const float4*)p; }
__device__ __forceinline__ float4 ld4(const u16* p) {
    uint2 v = *(const uint2*)p;
    float4 r;
    r.x = __uint_as_float((v.x & 0xffffu) << 16);
    r.y = __uint_as_float(v.x & 0xffff0000u);
    r.z = __uint_as_float((v.y & 0xffffu) << 16);
    r.w = __uint_as_float(v.y & 0xffff0000u);
    return r;
}
__device__ __forceinline__ void st4(float* p, float4 v) { *(float4*)p = v; }
__device__ __forceinline__ void st4(u16* p, float4 v) {
    uint2 o;
    o.x = (u32)f2bf(v.x) | ((u32)f2bf(v.y) << 16);
    o.y = (u32)f2bf(v.z) | ((u32)f2bf(v.w) << 16);
    *(uint2*)p = o;
}
// ---- scalar load/store ----------------------------------------------------
__device__ __forceinline__ float lds1(const float* p) { return *p; }
__device__ __forceinline__ float lds1(const u16* p) { return __uint_as_float(((u32)*p) << 16); }
__device__ __forceinline__ void sts1(float* p, float v) { *p = v; }
__device__ __forceinline__ void sts1(u16* p, float v) { *p = f2bf(v); }

// ---- 8-wide bf16 load -> 8 floats -----------------------------------------
__device__ __forceinline__ void ld8bf(const u16* p, float* v) {
    uint4 r = *(const uint4*)p;
    v[0] = __uint_as_float((r.x & 0xffffu) << 16);
    v[1] = __uint_as_float(r.x & 0xffff0000u);
    v[2] = __uint_as_float((r.y & 0xffffu) << 16);
    v[3] = __uint_as_float(r.y & 0xffff0000u);
    v[4] = __uint_as_float((r.z & 0xffffu) << 16);
    v[5] = __uint_as_float(r.z & 0xffff0000u);
    v[6] = __uint_as_float((r.w & 0xffffu) << 16);
    v[7] = __uint_as_float(r.w & 0xffff0000u);
}

// async global->LDS, 16B per lane (dest = wave-uniform base + lane*16)
__device__ __forceinline__ void glds16(const u16* g, u16* l) {
    __builtin_amdgcn_global_load_lds(
        (const __attribute__((address_space(1))) unsigned int*)g,
        (__attribute__((address_space(3))) unsigned int*)l, 16, 0, 0);
}

// ---------------------------------------------------------------------------
// Weight prep: fp32 [K][N] -> bf16 [N][K] (tiled LDS transpose, 32x32)
// ---------------------------------------------------------------------------
__global__ __launch_bounds__(256) void transpose_bf16_kernel(
    const float* __restrict__ in, u16* __restrict__ out, int K, int N)
{
    __shared__ float t[32][33];
    int bn = blockIdx.x * 32, bk = blockIdx.y * 32;
    int tx = threadIdx.x & 31, ty = threadIdx.x >> 5;   // 32 x 8
    #pragma unroll
    for (int i = 0; i < 32; i += 8)
        t[ty + i][tx] = in[(size_t)(bk + ty + i) * N + bn + tx];
    __syncthreads();
    #pragma unroll
    for (int i = 0; i < 32; i += 8)
        out[(size_t)(bn + ty + i) * K + bk + tx] = f2bf(t[tx][ty + i]);
}

// ---------------------------------------------------------------------------
// dw weight prep: [1024][9] fp32 -> [9][1024] fp32 (into d_out scratch)
// ---------------------------------------------------------------------------
__global__ __launch_bounds__(256) void dwprep_kernel(
    const float* __restrict__ in, float* __restrict__ out)
{
    int idx = blockIdx.x * 256 + threadIdx.x;   // 0..9215
    if (idx < 9 * HID) {
        int ch = idx / 9, t = idx - ch * 9;
        out[t * HID + ch] = in[idx];
    }
}

// ---------------------------------------------------------------------------
// LayerNorm over C=256: one wave (64 lanes) per row, 4 rows per 256-thr block
// ---------------------------------------------------------------------------
template<typename TI, typename TO>
__global__ __launch_bounds__(256) void ln_kernel(
    const TI* __restrict__ x, const float* __restrict__ g,
    const float* __restrict__ b, TO* __restrict__ y)
{
    int wave = threadIdx.x >> 6;
    int lane = threadIdx.x & 63;
    int row = blockIdx.x * 4 + wave;
    const TI* xr = x + (size_t)row * CDIM;
    float4 v = ld4(&xr[lane * 4]);
    float s  = v.x + v.y + v.z + v.w;
    float s2 = v.x*v.x + v.y*v.y + v.z*v.z + v.w*v.w;
    #pragma unroll
    for (int off = 32; off > 0; off >>= 1) {
        s  += __shfl_xor(s,  off);
        s2 += __shfl_xor(s2, off);
    }
    float mu   = s * (1.f / CDIM);
    float var  = s2 * (1.f / CDIM) - mu * mu;
    float rstd = rsqrtf(var + 1e-5f);
    float4 gv = *(const float4*)&g[lane * 4];
    float4 bv = *(const float4*)&b[lane * 4];
    float4 o;
    o.x = (v.x - mu) * rstd * gv.x + bv.x;
    o.y = (v.y - mu) * rstd * gv.y + bv.y;
    o.z = (v.z - mu) * rstd * gv.z + bv.z;
    o.w = (v.w - mu) * rstd * gv.w + bv.w;
    st4(&y[(size_t)row * CDIM + lane * 4], o);
}

// ---------------------------------------------------------------------------
// MFMA bf16 GEMM: C[M,N] = A[M,K](bf16) @ Bt[N,K](bf16)^T + bias (+res/+gelu)
// 128x128 tile, BK=32, 256 threads = 4 waves (2x2), each wave 64x64 via
// 4x4 fragments of mfma_f32_16x16x32_bf16. global_load_lds staging (m97).
// EPI: 0 = bias, 1 = bias + residual, 2 = bias + GELU
// ---------------------------------------------------------------------------
template<int EPI, typename TR, typename TO>
__global__ __launch_bounds__(256) void mgemm_kernel(
    const u16* __restrict__ A, const u16* __restrict__ Bt,
    const float* __restrict__ bias, const TR* __restrict__ res,
    TO* __restrict__ Cc, int N, int K)
{
    __shared__ u16 smem[8192];     // As[128][32] @0, Bs[128][32] @4096

    int tid  = threadIdx.x;
    int lane = tid & 63;
    int wave = tid >> 6;
    int wr = wave >> 1, wc = wave & 1;
    size_t bm = (size_t)blockIdx.y * 128;
    size_t bn = (size_t)blockIdx.x * 128;

    // staging source addresses (per lane): 16 rows per gload, 4 chunks/row
    int srow = wave * 32 + (lane >> 2);
    int scol = (lane & 3) * 8;
    const u16* ga = A  + (bm + srow) * K + scol;
    const u16* gb = Bt + (bn + srow) * K + scol;
    u16* laA0 = &smem[wave * 1024];
    u16* laA1 = &smem[wave * 1024 + 512];
    u16* laB0 = &smem[4096 + wave * 1024];
    u16* laB1 = &smem[4096 + wave * 1024 + 512];

    // fragment read offsets
    int ar = wr * 64 + (lane & 15);
    int br = wc * 64 + (lane & 15);
    int kc = (lane >> 4) * 8;

    f32x4 acc[4][4] = {};

    for (int kt = 0; kt < K; kt += 32) {
        glds16(ga, laA0);
        glds16(ga + 16 * K, laA1);
        glds16(gb, laB0);
        glds16(gb + 16 * K, laB1);
        ga += 32; gb += 32;
        __syncthreads();

        bf16x8 af[4], bfv[4];
        #pragma unroll
        for (int m = 0; m < 4; ++m)
            af[m] = *(const bf16x8*)&smem[(ar + m * 16) * 32 + kc];
        #pragma unroll
        for (int n = 0; n < 4; ++n)
            bfv[n] = *(const bf16x8*)&smem[4096 + (br + n * 16) * 32 + kc];
        #pragma unroll
        for (int m = 0; m < 4; ++m)
            #pragma unroll
            for (int n = 0; n < 4; ++n)
                acc[m][n] = __builtin_amdgcn_mfma_f32_16x16x32_bf16(
                    af[m], bfv[n], acc[m][n], 0, 0, 0);
        __syncthreads();
    }

    // epilogue: row = bm+wr*64+m*16+(lane>>4)*4+r, col = bn+wc*64+n*16+(lane&15)
    int colb = (int)bn + wc * 64 + (lane & 15);
    int rowb = (int)bm + wr * 64 + (lane >> 4) * 4;
    #pragma unroll
    for (int n = 0; n < 4; ++n) {
        float bv = bias[colb + n * 16];
        #pragma unroll
        for (int m = 0; m < 4; ++m) {
            #pragma unroll
            for (int r = 0; r < 4; ++r) {
                int row = rowb + m * 16 + r;
                float v = acc[m][n][r] + bv;
                if (EPI == 1) v += lds1(&res[(size_t)row * N + colb + n * 16]);
                if (EPI == 2) v = gelu_f(v);
                sts1(&Cc[(size_t)row * N + colb + n * 16], v);
            }
        }
    }
}

// ---------------------------------------------------------------------------
// MFMA windowed attention: one 64-thread wave per (window, head).
// QK^T (64x64x32) and PV (64x32x64) via mfma_f32_16x16x32_bf16.
// Q/K/V fragments load directly from global qkv (shifted-window gather).
// Softmax in C/D register layout; P routed through XOR-swizzled LDS.
// ---------------------------------------------------------------------------
__global__ __launch_bounds__(64) void attn_mfma_kernel(
    const u16* __restrict__ qkv, const float* __restrict__ bias_table,
    u16* __restrict__ out)
{
    __shared__ u16 P[NWIN * NWIN];   // [64 q][64 k] bf16, col ^= (row&7)<<3
    __shared__ int lbl[NWIN];

    int lane = threadIdx.x;
    int l15 = lane & 15;
    int hi  = lane >> 4;
    int widx = blockIdx.x;           // 0..511  (b*256 + wr*16 + wc)
    int head = blockIdx.y;           // 0..7
    int b  = widx >> 8;
    int w  = widx & 255;
    int wr = w >> 4, wc = w & 15;

    // window token n -> global token index (shift roll by +4 with wrap)
    auto tokof = [&](int n) -> int {
        int si = (wr * WINSZ + (n >> 3) + 4) & 127;
        int sj = (wc * WINSZ + (n & 7) + 4) & 127;
        return b * LTOK + si * HW + sj;
    };

    // labels (mask regions) in shifted coords
    {
        int i = wr * WINSZ + (lane >> 3);
        int j = wc * WINSZ + (lane & 7);
        int li = (i < 120) ? 0 : (i < 124 ? 1 : 2);
        int lj = (j < 120) ? 0 : (j < 124 ? 1 : 2);
        lbl[lane] = li * 3 + lj;
    }

    // ---- load Q & K fragments directly from global -------------------------
    // A/B-frag layout: row = frag*16 + (lane&15), k = (lane>>4)*8 + i
    bf16x8 qf[4], kf[4];
    #pragma unroll
    for (int m = 0; m < 4; ++m) {
        int t = tokof(m * 16 + l15);
        const u16* base = qkv + (size_t)t * 768 + head * DH + hi * 8;
        qf[m] = *(const bf16x8*)base;           // q slice
        kf[m] = *(const bf16x8*)(base + 256);   // k slice
    }

    // ---- gather V^T B-fragments: vf[nf][ks], lane holds d=nf*16+l15,
    //      keys k = ks*32 + hi*8 + i -------------------------------------
    bf16x8 vf[2][2];
    #pragma unroll
    for (int ks = 0; ks < 2; ++ks) {
        #pragma unroll
        for (int i = 0; i < 8; ++i) {
            int t = tokof(ks * 32 + hi * 8 + i);
            const u16* vb = qkv + (size_t)t * 768 + 512 + head * DH;
            vf[0][ks][i] = (short)vb[l15];
            vf[1][ks][i] = (short)vb[16 + l15];
        }
    }

    // ---- QK^T: S[q][k], fragments s[m][n] ---------------------------------
    f32x4 s[4][4];
    #pragma unroll
    for (int m = 0; m < 4; ++m)
        #pragma unroll
        for (int n = 0; n < 4; ++n) {
            f32x4 z = {0.f, 0.f, 0.f, 0.f};
            s[m][n] = __builtin_amdgcn_mfma_f32_16x16x32_bf16(qf[m], kf[n], z, 0, 0, 0);
        }

    __syncthreads();   // lbl visible

    // k-token labels for this lane's columns
    int klbl[4];
    #pragma unroll
    for (int n = 0; n < 4; ++n) klbl[n] = lbl[n * 16 + l15];

    // ---- softmax in C/D layout: row q = m*16+hi*4+r, col k = n*16+l15 -----
    const float SCALE = 0.17677669529663687f;  // 1/sqrt(32)
    float inv[4][4];
    #pragma unroll
    for (int m = 0; m < 4; ++m) {
        #pragma unroll
        for (int r = 0; r < 4; ++r) {
            int q = m * 16 + hi * 4 + r;
            int qlbl = lbl[q];
            int rq = q >> 3, cq = q & 7;
            float v[4];
            #pragma unroll
            for (int n = 0; n < 4; ++n) {
                int kn = n * 16 + l15;
                int idx = (rq - (kn >> 3) + 7) * 15 + (cq - (kn & 7) + 7);
                float bv = bias_table[idx * HEADS + head];
                v[n] = s[m][n][r] * SCALE + bv + ((klbl[n] != qlbl) ? -100.f : 0.f);
            }
            float rmax = fmaxf(fmaxf(v[0], v[1]), fmaxf(v[2], v[3]));
            #pragma unroll
            for (int off = 1; off < 16; off <<= 1)
                rmax = fmaxf(rmax, __shfl_xor(rmax, off));
            float p0 = __expf(v[0] - rmax), p1 = __expf(v[1] - rmax);
            float p2 = __expf(v[2] - rmax), p3 = __expf(v[3] - rmax);
            float ls = p0 + p1 + p2 + p3;
            #pragma unroll
            for (int off = 1; off < 16; off <<= 1)
                ls += __shfl_xor(ls, off);
            inv[m][r] = 1.f / ls;
            int sw = (q & 7) << 3;
            P[q * NWIN + ((0 * 16 + l15) ^ sw)] = f2bf(p0);
            P[q * NWIN + ((1 * 16 + l15) ^ sw)] = f2bf(p1);
            P[q * NWIN + ((2 * 16 + l15) ^ sw)] = f2bf(p2);
            P[q * NWIN + ((3 * 16 + l15) ^ sw)] = f2bf(p3);
        }
    }

    __syncthreads();   // P visible

    // ---- PV: O[q][d] = P @ V, acc o[m][nf] --------------------------------
    f32x4 o[4][2] = {};
    #pragma unroll
    for (int ks = 0; ks < 2; ++ks) {
        #pragma unroll
        for (int m = 0; m < 4; ++m) {
            int row = m * 16 + l15;
            int colb = (ks * 32 + hi * 8) ^ ((row & 7) << 3);
            bf16x8 pa = *(const bf16x8*)&P[row * NWIN + colb];
            #pragma unroll
            for (int nf = 0; nf < 2; ++nf)
                o[m][nf] = __builtin_amdgcn_mfma_f32_16x16x32_bf16(
                    pa, vf[nf][ks], o[m][nf], 0, 0, 0);
        }
    }

    // ---- epilogue: normalize rows, scatter to out -------------------------
    #pragma unroll
    for (int m = 0; m < 4; ++m) {
        #pragma unroll
        for (int r = 0; r < 4; ++r) {
            int q = m * 16 + hi * 4 + r;
            int t = tokof(q);
            u16* op = out + (size_t)t * CDIM + head * DH + l15;
            float iv = inv[m][r];
            op[0]  = f2bf(o[m][0][r] * iv);
            op[16] = f2bf(o[m][1][r] * iv);
        }
    }
}

// ---------------------------------------------------------------------------
// Depthwise 3x3 conv (NHWC, SAME zero-pad) + bias + GELU. bf16 in/out.
// Thread: 8 channels x 4 consecutive pixels along j (16B loads, j-overlap
// reuse: 18 row-loads for 4 outputs). Block: 8 pixels x 1024 ch. Grid 4096.
// wt9: [9][1024] fp32 tap-major table (pre-transposed, lives in d_out scratch)
// ---------------------------------------------------------------------------
__global__ __launch_bounds__(256) void dwconv_kernel(
    const u16* __restrict__ h, const float* __restrict__ wt9,
    const float* __restrict__ bias, u16* __restrict__ out)
{
    int blk = blockIdx.x;             // b*2048 + i*16 + jt
    int b   = blk >> 11;
    int rem = blk & 2047;
    int i   = rem >> 4;
    int jt  = rem & 15;
    int cg  = (threadIdx.x & 127) * 8;           // channel base (0..1016)
    int j0  = jt * 8 + (threadIdx.x >> 7) * 4;   // first of 4 output pixels

    float acc[4][8] = {};
    const u16* base = h + (size_t)b * LTOK * HID + cg;

    #pragma unroll
    for (int di = 0; di < 3; ++di) {
        int ii = i + di - 1;
        if (ii < 0 || ii >= HW) continue;
        const u16* rowp = base + (size_t)ii * HW * HID;
        float v[6][8];
        #pragma unroll
        for (int cc = 0; cc < 6; ++cc) {
            int jj = j0 - 1 + cc;
            if (jj >= 0 && jj < HW) {
                ld8bf(&rowp[(size_t)jj * HID], v[cc]);
            } else {
                #pragma unroll
                for (int q = 0; q < 8; ++q) v[cc][q] = 0.f;
            }
        }
        #pragma unroll
        for (int t = 0; t < 3; ++t) {
            const float* wp = &wt9[(di * 3 + t) * HID + cg];
            float4 wa = *(const float4*)wp;
            float4 wb = *(const float4*)(wp + 4);
            float w[8] = {wa.x, wa.y, wa.z, wa.w, wb.x, wb.y, wb.z, wb.w};
            #pragma unroll
            for (int p = 0; p < 4; ++p)
                #pragma unroll
                for (int q = 0; q < 8; ++q)
                    acc[p][q] += v[p + t][q] * w[q];
        }
    }

    float4 ba = *(const float4*)&bias[cg];
    float4 bb = *(const float4*)&bias[cg + 4];
    float bs[8] = {ba.x, ba.y, ba.z, ba.w, bb.x, bb.y, bb.z, bb.w};
    u16* ob = out + ((size_t)b * LTOK + (size_t)i * HW + j0) * HID + cg;
    #pragma unroll
    for (int p = 0; p < 4; ++p) {
        u32 o[4];
        #pragma unroll
        for (int q = 0; q < 4; ++q) {
            u16 lo = f2bf(gelu_f(acc[p][2 * q] + bs[2 * q]));
            u16 hi = f2bf(gelu_f(acc[p][2 * q + 1] + bs[2 * q + 1]));
            o[q] = (u32)lo | ((u32)hi << 16);
        }
        *(uint4*)(ob + (size_t)p * HID) = make_uint4(o[0], o[1], o[2], o[3]);
    }
}

// ---------------------------------------------------------------------------
extern "C" void kernel_launch(void* const* d_in, const int* in_sizes, int n_in,
                              void* d_out, int out_size, void* d_ws, size_t ws_size,
                              hipStream_t stream) {
    const float* x      = (const float*)d_in[0];
    const float* n1g    = (const float*)d_in[1];
    const float* n1b    = (const float*)d_in[2];
    const float* qkv_w  = (const float*)d_in[3];
    const float* qkv_b  = (const float*)d_in[4];
    const float* relb   = (const float*)d_in[5];
    const float* proj_w = (const float*)d_in[6];
    const float* proj_b = (const float*)d_in[7];
    const float* n2g    = (const float*)d_in[8];
    const float* n2b    = (const float*)d_in[9];
    const float* lin1_w = (const float*)d_in[10];
    const float* lin1_b = (const float*)d_in[11];
    const float* dw_w   = (const float*)d_in[12];
    const float* dw_b   = (const float*)d_in[13];
    const float* lin2_w = (const float*)d_in[14];
    const float* lin2_b = (const float*)d_in[15];
    float* out = (float*)d_out;

    // bf16 arena (9*M8 elems = 151 MB, same as passing round 4):
    //  R0 [0,4M8):   yn -> attn -> yn2 -> h2[0:4M8)
    //  R1 [M8,4M8):  qkv -> lin1_wt
    //  R2 [4M8,5M8): x1 (steps 4-8)
    //  R3 [5M8,9M8): qkv_wt+proj_wt (steps 0-4) -> hbuf (6-7) -> lin2_wt (8)
    u16* ws16 = (u16*)d_ws;
    const size_t M8 = (size_t)MTOK * CDIM;   // 8,388,608
    u16* yn      = ws16;
    u16* qkv     = ws16 + M8;
    u16* attn    = ws16;
    u16* x1      = ws16 + 4 * M8;
    u16* yn2     = ws16;
    u16* hbuf    = ws16 + 5 * M8;
    u16* h2      = ws16;
    u16* qkv_wt  = ws16 + 5 * M8;            // [768][256]
    u16* proj_wt = qkv_wt + 768 * 256;       // [256][256]
    u16* lin1_wt = ws16 + M8;                // [1024][256]
    u16* lin2_wt = ws16 + 5 * M8;            // [256][1024]
    float* wt9   = (float*)d_out;            // [9][1024] scratch; d_out dead
                                             // until step 8 fully overwrites it

    // 0) weight prep (qkv, proj)
    transpose_bf16_kernel<<<dim3(768 / 32, 256 / 32), 256, 0, stream>>>(qkv_w, qkv_wt, 256, 768);
    transpose_bf16_kernel<<<dim3(256 / 32, 256 / 32), 256, 0, stream>>>(proj_w, proj_wt, 256, 256);
    // 1) LN1: fp32 in, bf16 out
    ln_kernel<float, u16><<<MTOK / 4, 256, 0, stream>>>(x, n1g, n1b, yn);
    // 2) qkv = yn @ qkv_w + qkv_b
    mgemm_kernel<0, float, u16><<<dim3(768 / 128, MTOK / 128), 256, 0, stream>>>(
        yn, qkv_wt, qkv_b, (const float*)nullptr, qkv, 768, CDIM);
    // 3) windowed attention (MFMA)
    attn_mfma_kernel<<<dim3(512, HEADS), 64, 0, stream>>>(qkv, relb, attn);
    // weight prep (lin1) into R1 (qkv now dead); dw weights into d_out scratch
    transpose_bf16_kernel<<<dim3(1024 / 32, 256 / 32), 256, 0, stream>>>(lin1_w, lin1_wt, 256, 1024);
    dwprep_kernel<<<36, 256, 0, stream>>>(dw_w, wt9);
    // 4) x1 = attn @ proj_w + proj_b + x
    mgemm_kernel<1, float, u16><<<dim3(CDIM / 128, MTOK / 128), 256, 0, stream>>>(
        attn, proj_wt, proj_b, x, x1, CDIM, CDIM);
    // 5) LN2: bf16 in, bf16 out
    ln_kernel<u16, u16><<<MTOK / 4, 256, 0, stream>>>(x1, n2g, n2b, yn2);
    // 6) hbuf = gelu(yn2 @ lin1_w + lin1_b)
    mgemm_kernel<2, float, u16><<<dim3(HID / 128, MTOK / 128), 256, 0, stream>>>(
        yn2, lin1_wt, lin1_b, (const float*)nullptr, hbuf, HID, CDIM);
    // 7) h2 = gelu(dwconv3x3(hbuf) + dw_b)
    dwconv_kernel<<<BATCH * 2048, 256, 0, stream>>>(hbuf, wt9, dw_b, h2);
    // weight prep (lin2) into R3 (hbuf now dead)
    transpose_bf16_kernel<<<dim3(256 / 32, 1024 / 32), 256, 0, stream>>>(lin2_w, lin2_wt, 1024, 256);
    // 8) out = h2 @ lin2_w + lin2_b + x1   (fp32 out)
    mgemm_kernel<1, u16, float><<<dim3(CDIM / 128, MTOK / 128), 256, 0, stream>>>(
        h2, lin2_wt, lin2_b, x1, out, CDIM, HID);

    (void)in_sizes; (void)n_in; (void)out_size; (void)ws_size;
}